// Round 5
// baseline (294.035 us; speedup 1.0000x reference)
//
#include <hip/hip_runtime.h>

constexpr int kB  = 16;
constexpr int kLM = 1024;
constexpr int kLX = 1024;
constexpr int kD  = 768;

using short8 = __attribute__((ext_vector_type(8))) short;
using f32x4  = __attribute__((ext_vector_type(4))) float;

__device__ __forceinline__ unsigned short f2bf(float f) {
    unsigned u = __float_as_uint(f);
    u = (u + 0x7FFF + ((u >> 16) & 1)) >> 16;   // RNE
    return (unsigned short)u;
}
__device__ __forceinline__ float bf2f(unsigned short h) {
    return __uint_as_float(((unsigned)h) << 16);
}

// async 16B global->LDS copy; dst must be wave-uniform base + lane*16.
__device__ __forceinline__ void gl_lds16(const unsigned short* g, unsigned short* l) {
    auto gp = (const __attribute__((address_space(1))) unsigned int*)g;
    auto lp = (__attribute__((address_space(3))) unsigned int*)l;
    __builtin_amdgcn_global_load_lds(gp, lp, 16, 0, 0);
}

// cvt 8 fp32 -> one 16B bf16 chunk in LDS
__device__ __forceinline__ void writeChunk(unsigned short* dst, float4 lo, float4 hi) {
    union { short8 v; unsigned short u[8]; } o;
    o.u[0] = f2bf(lo.x); o.u[1] = f2bf(lo.y); o.u[2] = f2bf(lo.z); o.u[3] = f2bf(lo.w);
    o.u[4] = f2bf(hi.x); o.u[5] = f2bf(hi.y); o.u[6] = f2bf(hi.z); o.u[7] = f2bf(hi.w);
    *(short8*)dst = o.v;
}

// inverse XOR swizzle: LDS chunk index -> global (row, kseg) element offset
__device__ __forceinline__ size_t chunk_off(int c, int K) {
    int sr = c >> 3, s = c & 7;
    int tt = s ^ (sr & 7);
    int r  = sr * 2 + (tt >> 2);
    int q  = tt & 3;
    return (size_t)r * K + q * 8;
}

// ---------------------------------------------------------------------------
// Transpose + convert: xT[b][d][l] = bf16(x[b][l][d])
// ---------------------------------------------------------------------------
__global__ __launch_bounds__(256) void transpose_cvt_kernel(
    const float* __restrict__ x, unsigned short* __restrict__ xT) {
    __shared__ float tile[64][65];
    const int b  = blockIdx.z;
    const int l0 = blockIdx.x * 64;
    const int d0 = blockIdx.y * 64;
    const int t  = threadIdx.x;
    const int tx = t & 15, ty = t >> 4;
    const float* xb = x + ((size_t)b * kLX + l0) * kD + d0;
#pragma unroll
    for (int p = 0; p < 4; ++p) {
        int r = p * 16 + ty;
        float4 v = *(const float4*)(xb + (size_t)r * kD + tx * 4);
        *(float4*)&tile[r][tx * 4] = v;
    }
    __syncthreads();
    unsigned short* xTb = xT + ((size_t)b * kD + d0) * kLX + l0;
#pragma unroll
    for (int p = 0; p < 4; ++p) {
        int dr = p * 16 + ty;
        ushort4 o;
        o.x = f2bf(tile[tx * 4 + 0][dr]);
        o.y = f2bf(tile[tx * 4 + 1][dr]);
        o.z = f2bf(tile[tx * 4 + 2][dr]);
        o.w = f2bf(tile[tx * 4 + 3][dr]);
        *(ushort4*)(xTb + (size_t)dr * kLX + tx * 4) = o;
    }
}

// ---------------------------------------------------------------------------
// NT bf16 MFMA GEMM, 128x64 tile, BK=32, 256 thr (4 waves, 32 rows each).
// C[i][j] = sum_k A[i][k]*B[j][k]. XOR-swizzled 16B-chunk LDS (conflict-free).
// bf16 operands: global_load_lds (async, dbuf, 1 phase ahead).
// fp32 operands (AFP32/BFP32): 2-phase register pipeline — global float4x2
// loaded one iter ahead, cvt+ds_write_b128 into back buffer next iter.
// A tile = 512 chunks (2/thread), B tile = 256 chunks (1/thread).
// ---------------------------------------------------------------------------
template <bool AFP32, bool BFP32>
__global__ __launch_bounds__(256, 4) void gemm_nt_kernel(
    const void* __restrict__ Av, const void* __restrict__ Bv,
    unsigned short* __restrict__ C, int M, int N, int K,
    long sA, long sB, long sC) {
    __shared__ unsigned short Asm[2][128 * 32];   // 8 KB each
    __shared__ unsigned short Bsm[2][64 * 32];    // 4 KB each
    const int b  = blockIdx.z;
    const int i0 = blockIdx.x * 128;
    const int j0 = blockIdx.y * 64;
    const int t    = threadIdx.x;
    const int wave = t >> 6, lane = t & 63;
    const int quad = lane >> 4, l15 = lane & 15;

    const unsigned short* Abh = AFP32 ? nullptr
        : (const unsigned short*)Av + (size_t)b * sA + (size_t)i0 * K;
    const unsigned short* Bbh = BFP32 ? nullptr
        : (const unsigned short*)Bv + (size_t)b * sB + (size_t)j0 * K;
    const float* Abf = AFP32
        ? (const float*)Av + (size_t)b * sA + (size_t)i0 * K : nullptr;
    const float* Bbf = BFP32
        ? (const float*)Bv + (size_t)b * sB + (size_t)j0 * K : nullptr;

    const int cA0 = t, cA1 = t + 256, cB = t;
    const size_t offA0 = chunk_off(cA0, K);
    const size_t offA1 = chunk_off(cA1, K);
    const size_t offB  = chunk_off(cB, K);

    const int sfr  = ((l15 & 1) * 4 + quad) ^ ((l15 >> 1) & 7);
    const int aOff = wave * 1024 + (l15 >> 1) * 64 + sfr * 8;
    const int bOff = (l15 >> 1) * 64 + sfr * 8;

    f32x4 acc[2][4];
    const f32x4 z = {0.f, 0.f, 0.f, 0.f};
#pragma unroll
    for (int i = 0; i < 2; ++i)
#pragma unroll
        for (int j = 0; j < 4; ++j) acc[i][j] = z;

    const int T = K >> 5;
    float4 pa0, pa1, pa2, pa3, pb0, pb1;

    // ---- prologue: tile 0 into buf 0 ----
    if constexpr (AFP32) {
        float4 a0 = *(const float4*)(Abf + offA0);
        float4 a1 = *(const float4*)(Abf + offA0 + 4);
        float4 a2 = *(const float4*)(Abf + offA1);
        float4 a3 = *(const float4*)(Abf + offA1 + 4);
        writeChunk(Asm[0] + cA0 * 8, a0, a1);
        writeChunk(Asm[0] + cA1 * 8, a2, a3);
    } else {
        gl_lds16(Abh + offA0, Asm[0] + cA0 * 8);
        gl_lds16(Abh + offA1, Asm[0] + cA1 * 8);
    }
    if constexpr (BFP32) {
        float4 b0 = *(const float4*)(Bbf + offB);
        float4 b1 = *(const float4*)(Bbf + offB + 4);
        writeChunk(Bsm[0] + cB * 8, b0, b1);
    } else {
        gl_lds16(Bbh + offB, Bsm[0] + cB * 8);
    }
    // ---- preload regs for tile 1 (fp32 operands only) ----
    if constexpr (AFP32) {
        pa0 = *(const float4*)(Abf + offA0 + 32);
        pa1 = *(const float4*)(Abf + offA0 + 36);
        pa2 = *(const float4*)(Abf + offA1 + 32);
        pa3 = *(const float4*)(Abf + offA1 + 36);
    }
    if constexpr (BFP32) {
        pb0 = *(const float4*)(Bbf + offB + 32);
        pb1 = *(const float4*)(Bbf + offB + 36);
    }

    int buf = 0;
    for (int kt = 0; kt < T; ++kt) {
        __syncthreads();   // tile kt staged (async + ds_writes drained)
        if (kt + 1 < T) {
            const size_t k = (size_t)(kt + 1) << 5;
            if constexpr (AFP32) {
                writeChunk(Asm[buf ^ 1] + cA0 * 8, pa0, pa1);
                writeChunk(Asm[buf ^ 1] + cA1 * 8, pa2, pa3);
            } else {
                gl_lds16(Abh + offA0 + k, Asm[buf ^ 1] + cA0 * 8);
                gl_lds16(Abh + offA1 + k, Asm[buf ^ 1] + cA1 * 8);
            }
            if constexpr (BFP32) {
                writeChunk(Bsm[buf ^ 1] + cB * 8, pb0, pb1);
            } else {
                gl_lds16(Bbh + offB + k, Bsm[buf ^ 1] + cB * 8);
            }
        }
        if (kt + 2 < T) {
            const size_t k2 = (size_t)(kt + 2) << 5;
            if constexpr (AFP32) {
                pa0 = *(const float4*)(Abf + offA0 + k2);
                pa1 = *(const float4*)(Abf + offA0 + k2 + 4);
                pa2 = *(const float4*)(Abf + offA1 + k2);
                pa3 = *(const float4*)(Abf + offA1 + k2 + 4);
            }
            if constexpr (BFP32) {
                pb0 = *(const float4*)(Bbf + offB + k2);
                pb1 = *(const float4*)(Bbf + offB + k2 + 4);
            }
        }
        const unsigned short* aP = Asm[buf] + aOff;
        const unsigned short* bP = Bsm[buf] + bOff;
        short8 af[2], bg[4];
#pragma unroll
        for (int i = 0; i < 2; ++i) af[i] = *(const short8*)(aP + i * 512);
#pragma unroll
        for (int j = 0; j < 4; ++j) bg[j] = *(const short8*)(bP + j * 512);
#pragma unroll
        for (int i = 0; i < 2; ++i)
#pragma unroll
            for (int j = 0; j < 4; ++j)
                acc[i][j] = __builtin_amdgcn_mfma_f32_16x16x32_bf16(
                    af[i], bg[j], acc[i][j], 0, 0, 0);
        buf ^= 1;
    }

    // C/D layout: col = lane&15, row = quad*4 + reg  [m89/m91 verified]
    unsigned short* Cb = C + (size_t)b * sC + (size_t)(i0 + wave * 32) * N + j0;
#pragma unroll
    for (int i = 0; i < 2; ++i)
#pragma unroll
        for (int j = 0; j < 4; ++j)
#pragma unroll
            for (int r = 0; r < 4; ++r)
                Cb[(size_t)(i * 16 + quad * 4 + r) * N + j * 16 + l15] =
                    f2bf(acc[i][j][r]);
}

// ---------------------------------------------------------------------------
// Fused beta + pooled. Grid (64,16): 4 blocks/CU. Wave handles 4 rows.
// ---------------------------------------------------------------------------
__global__ __launch_bounds__(256) void pool_kernel(
    const float* __restrict__ mainp, const unsigned short* __restrict__ Aout,
    const float* __restrict__ w, float* __restrict__ out) {
    const int b     = blockIdx.y;
    const int chunk = blockIdx.x;           // 64 chunks of 16 rows
    const int wave  = threadIdx.x >> 6, lane = threadIdx.x & 63;
    float w1[12], w2[12], ps[12], pm[12];
#pragma unroll
    for (int s = 0; s < 12; ++s) {
        w1[s] = w[s * 64 + lane];
        w2[s] = w[kD + s * 64 + lane];
        ps[s] = 0.f; pm[s] = 0.f;
    }
#pragma unroll
    for (int rr = 0; rr < 4; ++rr) {
        const int row = chunk * 16 + rr * 4 + wave;
        const float* mr = mainp + ((size_t)b * kLM + row) * kD;
        const unsigned short* ar = Aout + ((size_t)b * kLM + row) * kD;
        float sv[12], mv[12], acc = 0.f;
#pragma unroll
        for (int s = 0; s < 12; ++s) {
            float m_ = mr[s * 64 + lane];
            float a_ = bf2f(ar[s * 64 + lane]);
            sv[s] = m_ - a_;
            mv[s] = m_ * a_;
            acc += sv[s] * w1[s] + mv[s] * w2[s];
        }
#pragma unroll
        for (int off = 32; off; off >>= 1) acc += __shfl_xor(acc, off);
#pragma unroll
        for (int s = 0; s < 12; ++s) { ps[s] += acc * sv[s]; pm[s] += acc * mv[s]; }
    }
    float* ob = out + (size_t)b * 2 * kD;
#pragma unroll
    for (int s = 0; s < 12; ++s) {
        atomicAdd(&ob[s * 64 + lane], ps[s]);
        atomicAdd(&ob[kD + s * 64 + lane], pm[s]);
    }
}

extern "C" void kernel_launch(void* const* d_in, const int* in_sizes, int n_in,
                              void* d_out, int out_size, void* d_ws, size_t ws_size,
                              hipStream_t stream) {
    const float* mainp = (const float*)d_in[0];  // (B, LM, D)
    const float* x     = (const float*)d_in[1];  // (B, LX, D)
    const float* W     = (const float*)d_in[2];  // (D, D)
    const float* w     = (const float*)d_in[3];  // (2D, 1)
    float* out = (float*)d_out;                  // (B, 2D)

    char* p = (char*)d_ws;
    unsigned short* xT = (unsigned short*)p; p += (size_t)kB * kD * kLX * 2;
    unsigned short* G  = (unsigned short*)p; p += (size_t)kB * kD * kD * 2;
    unsigned short* Mt = (unsigned short*)p; p += (size_t)kB * kD * kD * 2;
    unsigned short* Ao = (unsigned short*)p; p += (size_t)kB * kLM * kD * 2;

    hipMemsetAsync(out, 0, (size_t)kB * 2 * kD * sizeof(float), stream);

    transpose_cvt_kernel<<<dim3(kLX / 64, kD / 64, kB), 256, 0, stream>>>(x, xT);

    // G[b] = xT[b] @ xT[b]^T   (bf16 x bf16, both async)
    gemm_nt_kernel<false, false><<<dim3(kD / 128, kD / 64, kB), 256, 0, stream>>>(
        xT, xT, G, kD, kD, kLX, (long)kD * kLX, (long)kD * kLX, (long)kD * kD);
    // Mt[b] = G[b] @ W^T       (A = G bf16 async, B = W fp32 in-staging cvt)
    gemm_nt_kernel<false, true><<<dim3(kD / 128, kD / 64, kB), 256, 0, stream>>>(
        G, W, Mt, kD, kD, kD, (long)kD * kD, 0L, (long)kD * kD);
    // A[b] = main[b] @ Mt[b]^T (A = main fp32 in-staging cvt, B = Mt bf16 async)
    gemm_nt_kernel<true, false><<<dim3(kLM / 128, kD / 64, kB), 256, 0, stream>>>(
        mainp, Mt, Ao, kLM, kD, kD, (long)kLM * kD, (long)kD * kD, (long)kLM * kD);

    pool_kernel<<<dim3(kLM / 16, kB), 256, 0, stream>>>(mainp, Ao, w, out);
}

// Round 6
// 245.174 us; speedup vs baseline: 1.1993x; 1.1993x over previous
//
#include <hip/hip_runtime.h>

constexpr int kB  = 16;
constexpr int kLM = 1024;
constexpr int kLX = 1024;
constexpr int kD  = 768;

using short8 = __attribute__((ext_vector_type(8))) short;
using f32x4  = __attribute__((ext_vector_type(4))) float;

__device__ __forceinline__ unsigned short f2bf(float f) {
    unsigned u = __float_as_uint(f);
    u = (u + 0x7FFF + ((u >> 16) & 1)) >> 16;   // RNE
    return (unsigned short)u;
}
__device__ __forceinline__ float bf2f(unsigned short h) {
    return __uint_as_float(((unsigned)h) << 16);
}

// async 16B global->LDS copy; dst must be wave-uniform base + lane*16.
__device__ __forceinline__ void gl_lds16(const unsigned short* g, unsigned short* l) {
    auto gp = (const __attribute__((address_space(1))) unsigned int*)g;
    auto lp = (__attribute__((address_space(3))) unsigned int*)l;
    __builtin_amdgcn_global_load_lds(gp, lp, 16, 0, 0);
}

// cvt 8 fp32 -> one 16B bf16 chunk in LDS
__device__ __forceinline__ void writeChunk(unsigned short* dst, float4 lo, float4 hi) {
    union { short8 v; unsigned short u[8]; } o;
    o.u[0] = f2bf(lo.x); o.u[1] = f2bf(lo.y); o.u[2] = f2bf(lo.z); o.u[3] = f2bf(lo.w);
    o.u[4] = f2bf(hi.x); o.u[5] = f2bf(hi.y); o.u[6] = f2bf(hi.z); o.u[7] = f2bf(hi.w);
    *(short8*)dst = o.v;
}

// inverse XOR swizzle: LDS chunk index -> global (row, kseg) element offset
__device__ __forceinline__ size_t chunk_off(int c, int K) {
    int sr = c >> 3, s = c & 7;
    int tt = s ^ (sr & 7);
    int r  = sr * 2 + (tt >> 2);
    int q  = tt & 3;
    return (size_t)r * K + q * 8;
}

// ---------------------------------------------------------------------------
// Transpose + convert: xT[b][d][l] = bf16(x[b][l][d])
// ---------------------------------------------------------------------------
__global__ __launch_bounds__(256) void transpose_cvt_kernel(
    const float* __restrict__ x, unsigned short* __restrict__ xT) {
    __shared__ float tile[64][65];
    const int b  = blockIdx.z;
    const int l0 = blockIdx.x * 64;
    const int d0 = blockIdx.y * 64;
    const int t  = threadIdx.x;
    const int tx = t & 15, ty = t >> 4;
    const float* xb = x + ((size_t)b * kLX + l0) * kD + d0;
#pragma unroll
    for (int p = 0; p < 4; ++p) {
        int r = p * 16 + ty;
        float4 v = *(const float4*)(xb + (size_t)r * kD + tx * 4);
        *(float4*)&tile[r][tx * 4] = v;
    }
    __syncthreads();
    unsigned short* xTb = xT + ((size_t)b * kD + d0) * kLX + l0;
#pragma unroll
    for (int p = 0; p < 4; ++p) {
        int dr = p * 16 + ty;
        ushort4 o;
        o.x = f2bf(tile[tx * 4 + 0][dr]);
        o.y = f2bf(tile[tx * 4 + 1][dr]);
        o.z = f2bf(tile[tx * 4 + 2][dr]);
        o.w = f2bf(tile[tx * 4 + 3][dr]);
        *(ushort4*)(xTb + (size_t)dr * kLX + tx * 4) = o;
    }
}

// ---------------------------------------------------------------------------
// NT bf16 MFMA GEMM, 128x128 tile, BK=32, 256 thr (2x2 waves), 4x4 MFMA/wave.
// C[i][j] = sum_k A[i][k]*B[j][k]. XOR-swizzled 16B-chunk LDS (conflict-free).
// Double-buffered: barrier -> stage tile t+1 into back buffer -> compute t.
// bf16 operands via async global_load_lds; fp32 operands (AFP32/BFP32) via a
// 2-phase register pipeline (global float4 x4 one iter ahead, cvt+ds_write).
// NO min-waves clamp: R5's (256,4) forced VGPR=44 -> scratch spills.
// ---------------------------------------------------------------------------
template <bool AFP32, bool BFP32>
__global__ __launch_bounds__(256) void gemm_nt_kernel(
    const void* __restrict__ Av, const void* __restrict__ Bv,
    unsigned short* __restrict__ C, int M, int N, int K,
    long sA, long sB, long sC) {
    __shared__ unsigned short Asm[2][128 * 32];   // 8 KB each
    __shared__ unsigned short Bsm[2][128 * 32];
    const int b  = blockIdx.z;
    const int i0 = blockIdx.x * 128;
    const int j0 = blockIdx.y * 128;
    const int t    = threadIdx.x;
    const int wave = t >> 6, lane = t & 63;
    const int wr = (wave >> 1) * 64, wc = (wave & 1) * 64;
    const int quad = lane >> 4, l15 = lane & 15;

    const unsigned short* Abh = AFP32 ? nullptr
        : (const unsigned short*)Av + (size_t)b * sA + (size_t)i0 * K;
    const unsigned short* Bbh = BFP32 ? nullptr
        : (const unsigned short*)Bv + (size_t)b * sB + (size_t)j0 * K;
    const float* Abf = AFP32
        ? (const float*)Av + (size_t)b * sA + (size_t)i0 * K : nullptr;
    const float* Bbf = BFP32
        ? (const float*)Bv + (size_t)b * sB + (size_t)j0 * K : nullptr;

    const int c0 = t, c1 = t + 256;
    const size_t off0 = chunk_off(c0, K);
    const size_t off1 = chunk_off(c1, K);

    const int sfr  = ((l15 & 1) * 4 + quad) ^ ((l15 >> 1) & 7);
    const int aOff = wr * 32 + (l15 >> 1) * 64 + sfr * 8;
    const int bOff = wc * 32 + (l15 >> 1) * 64 + sfr * 8;

    f32x4 acc[4][4];
    const f32x4 z = {0.f, 0.f, 0.f, 0.f};
#pragma unroll
    for (int i = 0; i < 4; ++i)
#pragma unroll
        for (int j = 0; j < 4; ++j) acc[i][j] = z;

    const int T = K >> 5;
    float4 pa0, pa1, pa2, pa3, pb0, pb1, pb2, pb3;

    // ---- prologue: tile 0 into buf 0 ----
    if constexpr (AFP32) {
        writeChunk(Asm[0] + c0 * 8, *(const float4*)(Abf + off0),
                                    *(const float4*)(Abf + off0 + 4));
        writeChunk(Asm[0] + c1 * 8, *(const float4*)(Abf + off1),
                                    *(const float4*)(Abf + off1 + 4));
    } else {
        gl_lds16(Abh + off0, Asm[0] + c0 * 8);
        gl_lds16(Abh + off1, Asm[0] + c1 * 8);
    }
    if constexpr (BFP32) {
        writeChunk(Bsm[0] + c0 * 8, *(const float4*)(Bbf + off0),
                                    *(const float4*)(Bbf + off0 + 4));
        writeChunk(Bsm[0] + c1 * 8, *(const float4*)(Bbf + off1),
                                    *(const float4*)(Bbf + off1 + 4));
    } else {
        gl_lds16(Bbh + off0, Bsm[0] + c0 * 8);
        gl_lds16(Bbh + off1, Bsm[0] + c1 * 8);
    }
    // ---- preload regs for tile 1 (fp32 operands only) ----
    if constexpr (AFP32) {
        pa0 = *(const float4*)(Abf + off0 + 32);
        pa1 = *(const float4*)(Abf + off0 + 36);
        pa2 = *(const float4*)(Abf + off1 + 32);
        pa3 = *(const float4*)(Abf + off1 + 36);
    }
    if constexpr (BFP32) {
        pb0 = *(const float4*)(Bbf + off0 + 32);
        pb1 = *(const float4*)(Bbf + off0 + 36);
        pb2 = *(const float4*)(Bbf + off1 + 32);
        pb3 = *(const float4*)(Bbf + off1 + 36);
    }

    int buf = 0;
    for (int kt = 0; kt < T; ++kt) {
        __syncthreads();   // tile kt staged (vmcnt + lgkm drained by compiler)
        if (kt + 1 < T) {
            const size_t k = (size_t)(kt + 1) << 5;
            if constexpr (AFP32) {
                writeChunk(Asm[buf ^ 1] + c0 * 8, pa0, pa1);
                writeChunk(Asm[buf ^ 1] + c1 * 8, pa2, pa3);
            } else {
                gl_lds16(Abh + off0 + k, Asm[buf ^ 1] + c0 * 8);
                gl_lds16(Abh + off1 + k, Asm[buf ^ 1] + c1 * 8);
            }
            if constexpr (BFP32) {
                writeChunk(Bsm[buf ^ 1] + c0 * 8, pb0, pb1);
                writeChunk(Bsm[buf ^ 1] + c1 * 8, pb2, pb3);
            } else {
                gl_lds16(Bbh + off0 + k, Bsm[buf ^ 1] + c0 * 8);
                gl_lds16(Bbh + off1 + k, Bsm[buf ^ 1] + c1 * 8);
            }
        }
        if (kt + 2 < T) {
            const size_t k2 = (size_t)(kt + 2) << 5;
            if constexpr (AFP32) {
                pa0 = *(const float4*)(Abf + off0 + k2);
                pa1 = *(const float4*)(Abf + off0 + k2 + 4);
                pa2 = *(const float4*)(Abf + off1 + k2);
                pa3 = *(const float4*)(Abf + off1 + k2 + 4);
            }
            if constexpr (BFP32) {
                pb0 = *(const float4*)(Bbf + off0 + k2);
                pb1 = *(const float4*)(Bbf + off0 + k2 + 4);
                pb2 = *(const float4*)(Bbf + off1 + k2);
                pb3 = *(const float4*)(Bbf + off1 + k2 + 4);
            }
        }
        const unsigned short* aP = Asm[buf] + aOff;
        const unsigned short* bP = Bsm[buf] + bOff;
        short8 af[4], bg[4];
#pragma unroll
        for (int i = 0; i < 4; ++i) af[i] = *(const short8*)(aP + i * 512);
#pragma unroll
        for (int j = 0; j < 4; ++j) bg[j] = *(const short8*)(bP + j * 512);
#pragma unroll
        for (int i = 0; i < 4; ++i)
#pragma unroll
            for (int j = 0; j < 4; ++j)
                acc[i][j] = __builtin_amdgcn_mfma_f32_16x16x32_bf16(
                    af[i], bg[j], acc[i][j], 0, 0, 0);
        buf ^= 1;
    }

    // C/D layout: col = lane&15, row = quad*4 + reg  [m89/m91 verified]
    unsigned short* Cb = C + (size_t)b * sC + (size_t)(i0 + wr) * N + j0 + wc;
#pragma unroll
    for (int i = 0; i < 4; ++i)
#pragma unroll
        for (int j = 0; j < 4; ++j)
#pragma unroll
            for (int r = 0; r < 4; ++r)
                Cb[(size_t)(i * 16 + quad * 4 + r) * N + j * 16 + l15] =
                    f2bf(acc[i][j][r]);
}

// ---------------------------------------------------------------------------
// Fused beta + pooled. Grid (64,16): 4 blocks/CU. Wave handles 4 rows.
// Cross-wave LDS pre-reduction -> 1 atomicAdd per (s,lane) per block (4x fewer).
// ---------------------------------------------------------------------------
__global__ __launch_bounds__(256) void pool_kernel(
    const float* __restrict__ mainp, const unsigned short* __restrict__ Aout,
    const float* __restrict__ w, float* __restrict__ out) {
    __shared__ float red[4][24][64];   // 24 KB
    const int b     = blockIdx.y;
    const int chunk = blockIdx.x;           // 64 chunks of 16 rows
    const int t     = threadIdx.x;
    const int wave  = t >> 6, lane = t & 63;
    float w1[12], w2[12], ps[12], pm[12];
#pragma unroll
    for (int s = 0; s < 12; ++s) {
        w1[s] = w[s * 64 + lane];
        w2[s] = w[kD + s * 64 + lane];
        ps[s] = 0.f; pm[s] = 0.f;
    }
#pragma unroll
    for (int rr = 0; rr < 4; ++rr) {
        const int row = chunk * 16 + rr * 4 + wave;
        const float* mr = mainp + ((size_t)b * kLM + row) * kD;
        const unsigned short* ar = Aout + ((size_t)b * kLM + row) * kD;
        float sv[12], mv[12], acc = 0.f;
#pragma unroll
        for (int s = 0; s < 12; ++s) {
            float m_ = mr[s * 64 + lane];
            float a_ = bf2f(ar[s * 64 + lane]);
            sv[s] = m_ - a_;
            mv[s] = m_ * a_;
            acc += sv[s] * w1[s] + mv[s] * w2[s];
        }
#pragma unroll
        for (int off = 32; off; off >>= 1) acc += __shfl_xor(acc, off);
#pragma unroll
        for (int s = 0; s < 12; ++s) { ps[s] += acc * sv[s]; pm[s] += acc * mv[s]; }
    }
#pragma unroll
    for (int s = 0; s < 12; ++s) {
        red[wave][s][lane]      = ps[s];
        red[wave][12 + s][lane] = pm[s];
    }
    __syncthreads();
    float* ob = out + (size_t)b * 2 * kD;
    for (int v = t; v < 24 * 64; v += 256) {
        const int sl = v >> 6, ln = v & 63;
        const float sum = red[0][sl][ln] + red[1][sl][ln] +
                          red[2][sl][ln] + red[3][sl][ln];
        const int d = (sl < 12) ? sl * 64 + ln : kD + (sl - 12) * 64 + ln;
        atomicAdd(&ob[d], sum);
    }
}

extern "C" void kernel_launch(void* const* d_in, const int* in_sizes, int n_in,
                              void* d_out, int out_size, void* d_ws, size_t ws_size,
                              hipStream_t stream) {
    const float* mainp = (const float*)d_in[0];  // (B, LM, D)
    const float* x     = (const float*)d_in[1];  // (B, LX, D)
    const float* W     = (const float*)d_in[2];  // (D, D)
    const float* w     = (const float*)d_in[3];  // (2D, 1)
    float* out = (float*)d_out;                  // (B, 2D)

    char* p = (char*)d_ws;
    unsigned short* xT = (unsigned short*)p; p += (size_t)kB * kD * kLX * 2;
    unsigned short* G  = (unsigned short*)p; p += (size_t)kB * kD * kD * 2;
    unsigned short* Mt = (unsigned short*)p; p += (size_t)kB * kD * kD * 2;
    unsigned short* Ao = (unsigned short*)p; p += (size_t)kB * kLM * kD * 2;

    hipMemsetAsync(out, 0, (size_t)kB * 2 * kD * sizeof(float), stream);

    transpose_cvt_kernel<<<dim3(kLX / 64, kD / 64, kB), 256, 0, stream>>>(x, xT);

    // G[b] = xT[b] @ xT[b]^T   (bf16 x bf16, both async)
    gemm_nt_kernel<false, false><<<dim3(kD / 128, kD / 128, kB), 256, 0, stream>>>(
        xT, xT, G, kD, kD, kLX, (long)kD * kLX, (long)kD * kLX, (long)kD * kD);
    // Mt[b] = G[b] @ W^T       (A = G bf16 async, B = W fp32 in-staging cvt)
    gemm_nt_kernel<false, true><<<dim3(kD / 128, kD / 128, kB), 256, 0, stream>>>(
        G, W, Mt, kD, kD, kD, (long)kD * kD, 0L, (long)kD * kD);
    // A[b] = main[b] @ Mt[b]^T (A = main fp32 in-staging cvt, B = Mt bf16 async)
    gemm_nt_kernel<true, false><<<dim3(kLM / 128, kD / 128, kB), 256, 0, stream>>>(
        mainp, Mt, Ao, kLM, kD, kD, (long)kLM * kD, (long)kD * kD, (long)kLM * kD);

    pool_kernel<<<dim3(kLM / 16, kB), 256, 0, stream>>>(mainp, Ao, w, out);
}